// Round 13
// baseline (160.911 us; speedup 1.0000x reference)
//
#include <hip/hip_runtime.h>
#include <hip/hip_bf16.h>
#include <math.h>

#define EPS 1e-5f

typedef __attribute__((ext_vector_type(8))) short bf16x8;
typedef __attribute__((ext_vector_type(4))) float f32x4;
typedef __attribute__((ext_vector_type(16))) float f32x16;

#define MFMA16 __builtin_amdgcn_mfma_f32_16x16x32_bf16
#define MFMA32 __builtin_amdgcn_mfma_f32_32x32x16_bf16

__device__ __forceinline__ short f2bf(float x) {
    union { float f; unsigned u; } un; un.f = x;
    unsigned r = un.u + 0x7FFF + ((un.u >> 16) & 1);  // RNE
    return (short)(r >> 16);
}
__device__ __forceinline__ float bf2f(short s) {
    union { unsigned u; float f; } un;
    un.u = ((unsigned)(unsigned short)s) << 16;
    return un.f;
}
__device__ __forceinline__ unsigned pack_bf2(float a, float b) {
    unsigned r;
    asm("v_cvt_pk_bf16_f32 %0, %1, %2" : "=v"(r) : "v"(a), "v"(b));
    return r;
}
__device__ __forceinline__ float exp2_fast(float x) {
    float r;
    asm("v_exp_f32 %0, %1" : "=v"(r) : "v"(x));
    return r;
}
// v_permlane32_swap_b32: a.hi-lanes <-> b.lo-lanes (both modified)
__device__ __forceinline__ void permswap(unsigned& a, unsigned& b) {
    asm volatile("v_permlane32_swap_b32 %0, %1" : "+v"(a), "+v"(b));
}
__device__ __forceinline__ bf16x8 mk_frag(unsigned a, unsigned b, unsigned c, unsigned d) {
    union { unsigned u[4]; bf16x8 v; } t;
    t.u[0] = a; t.u[1] = b; t.u[2] = c; t.u[3] = d;
    return t.v;
}
__device__ __forceinline__ void load_lds16(const short* g, short* l) {
    __builtin_amdgcn_global_load_lds(
        (const __attribute__((address_space(1))) unsigned int*)g,
        (__attribute__((address_space(3))) unsigned int*)l, 16, 0, 0);
}
__device__ __forceinline__ void wait_vm0_barrier() {
    asm volatile("s_waitcnt vmcnt(0)" ::: "memory");
    __builtin_amdgcn_s_barrier();
    __builtin_amdgcn_sched_barrier(0);
}

// ---------------- fused prep: ln1 (blocks [0,2048)) + weight transp (blocks [2048,4608)) ----------------
struct WT { const float* w; short* t; int K; int N; };
struct WT7 { WT a[7]; };
__global__ __launch_bounds__(256) void prep_kernel(const float* __restrict__ in,
                                                   const float* __restrict__ lw,
                                                   const float* __restrict__ lb,
                                                   short* __restrict__ lo,
                                                   WT7 p) {
    __shared__ short t[32][33];
    int bid = blockIdx.x;
    if (bid < 2048) {
        // ---- LayerNorm: one wave per row, 4 rows/block ----
        int wv = threadIdx.x >> 6, lane = threadIdx.x & 63;
        int row = bid * 4 + wv;
        const float* x = in + (size_t)row * 512 + lane * 8;
        float4 v0 = *(const float4*)x;
        float4 v1 = *(const float4*)(x + 4);
        float s  = (v0.x + v0.y) + (v0.z + v0.w) + (v1.x + v1.y) + (v1.z + v1.w);
        float s2 = v0.x*v0.x + v0.y*v0.y + v0.z*v0.z + v0.w*v0.w
                 + v1.x*v1.x + v1.y*v1.y + v1.z*v1.z + v1.w*v1.w;
#pragma unroll
        for (int off = 1; off < 64; off <<= 1) {
            s  += __shfl_xor(s, off);
            s2 += __shfl_xor(s2, off);
        }
        float mu = s * (1.f / 512.f);
        float rstd = rsqrtf(s2 * (1.f / 512.f) - mu * mu + EPS);
        const float4 wa = *(const float4*)&lw[lane * 8];
        const float4 wb = *(const float4*)&lw[lane * 8 + 4];
        const float4 ba = *(const float4*)&lb[lane * 8];
        const float4 bv = *(const float4*)&lb[lane * 8 + 4];
        uint4 o;
        o.x = pack_bf2((v0.x - mu) * rstd * wa.x + ba.x, (v0.y - mu) * rstd * wa.y + ba.y);
        o.y = pack_bf2((v0.z - mu) * rstd * wa.z + ba.z, (v0.w - mu) * rstd * wa.w + ba.w);
        o.z = pack_bf2((v1.x - mu) * rstd * wb.x + bv.x, (v1.y - mu) * rstd * wb.y + bv.y);
        o.w = pack_bf2((v1.z - mu) * rstd * wb.z + bv.z, (v1.w - mu) * rstd * wb.w + bv.w);
        *(uint4*)&lo[(size_t)row * 512 + lane * 8] = o;
    } else {
        // ---- weight transpose+cast: w[K][N] fp32 -> t[N][K] bf16, 32x32 tiles ----
        int ti = bid - 2048;   // [0,2560): wq,wk,wv,wo 256 ea; gate,up,down 512 ea
        int e_idx, base;
        if (ti < 1024)      { e_idx = ti >> 8; base = e_idx << 8; }
        else if (ti < 1536) { e_idx = 4; base = 1024; }
        else if (ti < 2048) { e_idx = 5; base = 1536; }
        else                { e_idx = 6; base = 2048; }
        WT e = p.a[e_idx];
        int lt = ti - base;
        int nk = e.K >> 5;
        int k0 = (lt % nk) * 32, n0 = (lt / nk) * 32;
        int tx = threadIdx.x & 31, ty = threadIdx.x >> 5;  // 32 x 8
#pragma unroll
        for (int pp = 0; pp < 4; pp++)
            t[pp * 8 + ty][tx] = f2bf(e.w[(size_t)(k0 + pp * 8 + ty) * e.N + n0 + tx]);
        __syncthreads();
#pragma unroll
        for (int pp = 0; pp < 4; pp++)
            e.t[(size_t)(n0 + pp * 8 + ty) * e.K + k0 + tx] = t[tx][pp * 8 + ty];
    }
}

// ---------------- LayerNorm standalone (for ln2) ----------------
__global__ __launch_bounds__(256) void ln_kernel_b(const float* __restrict__ in,
                                                   const float* __restrict__ w,
                                                   const float* __restrict__ bb,
                                                   short* __restrict__ out) {
    int wv = threadIdx.x >> 6, lane = threadIdx.x & 63;
    int row = blockIdx.x * 4 + wv;
    const float* x = in + (size_t)row * 512 + lane * 8;
    float4 v0 = *(const float4*)x;
    float4 v1 = *(const float4*)(x + 4);
    float s  = (v0.x + v0.y) + (v0.z + v0.w) + (v1.x + v1.y) + (v1.z + v1.w);
    float s2 = v0.x*v0.x + v0.y*v0.y + v0.z*v0.z + v0.w*v0.w
             + v1.x*v1.x + v1.y*v1.y + v1.z*v1.z + v1.w*v1.w;
#pragma unroll
    for (int off = 1; off < 64; off <<= 1) {
        s  += __shfl_xor(s, off);
        s2 += __shfl_xor(s2, off);
    }
    float mu = s * (1.f / 512.f);
    float rstd = rsqrtf(s2 * (1.f / 512.f) - mu * mu + EPS);
    const float4 wa = *(const float4*)&w[lane * 8];
    const float4 wb = *(const float4*)&w[lane * 8 + 4];
    const float4 ba = *(const float4*)&bb[lane * 8];
    const float4 bv = *(const float4*)&bb[lane * 8 + 4];
    uint4 o;
    o.x = pack_bf2((v0.x - mu) * rstd * wa.x + ba.x, (v0.y - mu) * rstd * wa.y + ba.y);
    o.y = pack_bf2((v0.z - mu) * rstd * wa.z + ba.z, (v0.w - mu) * rstd * wa.w + ba.w);
    o.z = pack_bf2((v1.x - mu) * rstd * wb.x + bv.x, (v1.y - mu) * rstd * wb.y + bv.y);
    o.w = pack_bf2((v1.z - mu) * rstd * wb.z + bv.z, (v1.w - mu) * rstd * wb.w + bv.w);
    *(uint4*)&out[(size_t)row * 512 + lane * 8] = o;
}

// ---------------- bf16 MFMA GEMM: C[M,N] = A[M,K] @ Bt[N,K]^T ----------------
// 128xBN tile, BK=64, 4 waves 2x2, double-buffered LDS, 2-phase pipeline
// (stage(t+1) -> compute(t) -> vmcnt(0)+barrier), XCD swizzle.
// EPI: 0 = fp32 C = res + acc (row-major)
//      2 = bf16 qkv: q,k packed [b,h,l,d] (q pre-scaled by 0.125*log2e);
//          v written direct-transposed [b,h,d,l]  (proven R8 epilogue)
template <int EPI, int BM, int BN>
__global__ __launch_bounds__(256) void gemm_mfma(const short* __restrict__ A,
                                                 const short* __restrict__ Bt,
                                                 const float* __restrict__ res,
                                                 void* __restrict__ Cv,
                                                 int M, int N, int K) {
    constexpr int MI = BM >> 5;
    constexpr int NJ = BN >> 5;
    __shared__ short As[2][BM * 64];
    __shared__ short Bs[2][BN * 64];
    const int tid = threadIdx.x;
    const int lane = tid & 63, w = tid >> 6;
    const int g = lane >> 4, r16 = lane & 15;
    const int wr = w >> 1, wc = w & 1;

    // XCD-aware bijective swizzle (grid size divisible by 8)
    const int nb = gridDim.x * gridDim.y;
    const int fid = blockIdx.y * gridDim.x + blockIdx.x;
    const int nid = (fid & 7) * (nb >> 3) + (fid >> 3);
    const int m0 = (nid / gridDim.x) * BM, n0 = (nid % gridDim.x) * BN;

    const int lr = lane >> 3;        // row within 8-row group
    const int ck = (lane & 7) ^ lr;  // inverse-swizzled source chunk

    auto stage = [&](int buf, int k0) {
#pragma unroll
        for (int p = 0; p < BM / 32; p++) {
            int rb = w * (BM / 4) + p * 8;
            load_lds16(&A[(size_t)(m0 + rb + lr) * K + k0 + ck * 8], &As[buf][rb * 64]);
        }
#pragma unroll
        for (int p = 0; p < BN / 32; p++) {
            int rb = w * (BN / 4) + p * 8;
            load_lds16(&Bt[(size_t)(n0 + rb + lr) * K + k0 + ck * 8], &Bs[buf][rb * 64]);
        }
    };

    f32x4 acc[MI][NJ] = {};
    stage(0, 0);
    wait_vm0_barrier();

    const int nt = K >> 6;
    int cur = 0;
    for (int t = 0; t < nt; t++) {
        if (t + 1 < nt) stage(cur ^ 1, (t + 1) << 6);
#pragma unroll
        for (int ks = 0; ks < 2; ks++) {
            bf16x8 av[MI], bv[NJ];
#pragma unroll
            for (int i = 0; i < MI; i++) {
                int row = wr * (BM >> 1) + i * 16 + r16;
                av[i] = *(const bf16x8*)&As[cur][row * 64 + ((ks * 4 + g) ^ (row & 7)) * 8];
            }
#pragma unroll
            for (int j = 0; j < NJ; j++) {
                int row = wc * (BN >> 1) + j * 16 + r16;
                bv[j] = *(const bf16x8*)&Bs[cur][row * 64 + ((ks * 4 + g) ^ (row & 7)) * 8];
            }
#pragma unroll
            for (int i = 0; i < MI; i++)
#pragma unroll
                for (int j = 0; j < NJ; j++)
                    acc[i][j] = MFMA16(av[i], bv[j], acc[i][j], 0, 0, 0);
        }
        wait_vm0_barrier();
        cur ^= 1;
    }

#pragma unroll
    for (int i = 0; i < MI; i++)
#pragma unroll
        for (int j = 0; j < NJ; j++)
#pragma unroll
            for (int jr = 0; jr < 4; jr++) {
                int m = m0 + wr * (BM >> 1) + i * 16 + 4 * g + jr;
                int n = n0 + wc * (BN >> 1) + j * 16 + r16;
                float v = acc[i][j][jr];
                if (EPI == 0) {
                    size_t idx = (size_t)m * N + n;
                    ((float*)Cv)[idx] = res[idx] + v;
                } else {
                    if (n < 512) v *= 0.18033688011112042f;  // 0.125 * log2(e)
                    if (n < 1024) {
                        // q,k packed [b,h,l,d]
                        ((short*)Cv)[(size_t)(n >> 9) * 4194304 +
                                     (((size_t)(m >> 11) * 8 + ((n >> 6) & 7)) * 2048 + (m & 2047)) * 64 + (n & 63)] = f2bf(v);
                    } else {
                        // v direct-transposed [b,h,d,l]
                        ((short*)Cv)[(size_t)2 * 4194304 +
                                     (((size_t)(m >> 11) * 8 + ((n >> 6) & 7)) * 64 + (n & 63)) * 2048 + (m & 2047)] = f2bf(v);
                    }
                }
            }
}

// ---------------- fused FFN gate+up GEMM + silu: u = silu(A@Wg^T) * (A@Wu^T) ----------------
// 128x64 tile, BK=64, both B-panels staged, two accumulator sets; silu on fp32 gate.
__global__ __launch_bounds__(256) void ffn_gateup_kernel(const short* __restrict__ A,
                                                         const short* __restrict__ Bg,
                                                         const short* __restrict__ Bu,
                                                         short* __restrict__ U,
                                                         int M, int N, int K) {
    constexpr int BM = 128, BN = 64;
    constexpr int MI = 4, NJ = 2;
    __shared__ short As[2][BM * 64];
    __shared__ short Bgs[2][BN * 64];
    __shared__ short Bus[2][BN * 64];
    const int tid = threadIdx.x;
    const int lane = tid & 63, w = tid >> 6;
    const int g = lane >> 4, r16 = lane & 15;
    const int wr = w >> 1, wc = w & 1;

    const int nb = gridDim.x * gridDim.y;
    const int fid = blockIdx.y * gridDim.x + blockIdx.x;
    const int nid = (fid & 7) * (nb >> 3) + (fid >> 3);
    const int m0 = (nid / gridDim.x) * BM, n0 = (nid % gridDim.x) * BN;

    const int lr = lane >> 3;
    const int ck = (lane & 7) ^ lr;

    auto stage = [&](int buf, int k0) {
#pragma unroll
        for (int p = 0; p < 4; p++) {
            int rb = w * 32 + p * 8;
            load_lds16(&A[(size_t)(m0 + rb + lr) * K + k0 + ck * 8], &As[buf][rb * 64]);
        }
#pragma unroll
        for (int p = 0; p < 2; p++) {
            int rb = w * 16 + p * 8;
            load_lds16(&Bg[(size_t)(n0 + rb + lr) * K + k0 + ck * 8], &Bgs[buf][rb * 64]);
            load_lds16(&Bu[(size_t)(n0 + rb + lr) * K + k0 + ck * 8], &Bus[buf][rb * 64]);
        }
    };

    f32x4 accg[MI][NJ] = {};
    f32x4 accu[MI][NJ] = {};
    stage(0, 0);
    wait_vm0_barrier();

    const int nt = K >> 6;
    int cur = 0;
    for (int t = 0; t < nt; t++) {
        if (t + 1 < nt) stage(cur ^ 1, (t + 1) << 6);
#pragma unroll
        for (int ks = 0; ks < 2; ks++) {
            bf16x8 av[MI], bgv[NJ], buv[NJ];
#pragma unroll
            for (int i = 0; i < MI; i++) {
                int row = wr * 64 + i * 16 + r16;
                av[i] = *(const bf16x8*)&As[cur][row * 64 + ((ks * 4 + g) ^ (row & 7)) * 8];
            }
#pragma unroll
            for (int j = 0; j < NJ; j++) {
                int row = wc * 32 + j * 16 + r16;
                int off = row * 64 + ((ks * 4 + g) ^ (row & 7)) * 8;
                bgv[j] = *(const bf16x8*)&Bgs[cur][off];
                buv[j] = *(const bf16x8*)&Bus[cur][off];
            }
#pragma unroll
            for (int i = 0; i < MI; i++)
#pragma unroll
                for (int j = 0; j < NJ; j++) {
                    accg[i][j] = MFMA16(av[i], bgv[j], accg[i][j], 0, 0, 0);
                    accu[i][j] = MFMA16(av[i], buv[j], accu[i][j], 0, 0, 0);
                }
        }
        wait_vm0_barrier();
        cur ^= 1;
    }

#pragma unroll
    for (int i = 0; i < MI; i++)
#pragma unroll
        for (int j = 0; j < NJ; j++)
#pragma unroll
            for (int jr = 0; jr < 4; jr++) {
                int m = m0 + wr * 64 + i * 16 + 4 * g + jr;
                int n = n0 + wc * 32 + j * 16 + r16;
                float gt = accg[i][j][jr];
                float y = gt / (1.f + __expf(-gt)) * accu[i][j][jr];
                U[(size_t)m * N + n] = f2bf(y);
            }
}

// ---------------- MFMA flash attention: 32x32 swapped-QK, in-register softmax ----------------
// grid 512 (XCD-swizzled, bh-major), 4 waves, 32 q-rows/wave (Q-tile 128), KVBLK 64.
// Sequential over full L (numerics-proven, absmax 0.109). S^T = mfma32(K, Q): lane
// owns q = lane&31. P in-register via cvt_pk + permlane32_swap; O^T = mfma32(V^T, P).
__global__ __launch_bounds__(256) void attn_mfma_kernel(const short* __restrict__ qb,
                                                        const short* __restrict__ kb,
                                                        const short* __restrict__ vt,
                                                        short* __restrict__ outb) {
    __shared__ short SM[16384];  // [0,8K)=K dbuf, [8K,16K)=V dbuf (Q staged here first)

    const int fid = blockIdx.y * gridDim.x + blockIdx.x;   // grid (16, 32)
    const int nid = (fid & 7) * 64 + (fid >> 3);           // bh-major within XCD
    const int bh = nid >> 4, qt = nid & 15;
    const int b = bh >> 3, h = bh & 7;
    const int q0 = qt * 128;
    const size_t hb = (size_t)bh * (2048 * 64);

    const int tid = threadIdx.x;
    const int lane = tid & 63, w = tid >> 6;
    const int hi = lane >> 5;
    const int l31 = lane & 31;
    const int lr = lane >> 3, ck = (lane & 7) ^ lr;

    // ---- stage Q (wave w -> rows 32w..32w+31) into V-buffer area, then to regs ----
#pragma unroll
    for (int p = 0; p < 4; p++)
        load_lds16(&qb[hb + (size_t)(q0 + 32 * w + 8 * p + lr) * 64 + ck * 8],
                   &SM[8192 + (32 * w + 8 * p) * 64]);
    wait_vm0_barrier();
    bf16x8 qf[4];
    {
        int row = 32 * w + l31;
#pragma unroll
        for (int ds = 0; ds < 4; ds++)
            qf[ds] = *(const bf16x8*)&SM[8192 + row * 64 + ((2 * ds + hi) ^ (row & 7)) * 8];
    }
    asm volatile("s_waitcnt lgkmcnt(0)" ::: "memory");
    __builtin_amdgcn_s_barrier();
    __builtin_amdgcn_sched_barrier(0);

    auto stageKV = [&](int buf, int kt) {
        int k0 = kt * 64;
        int rb = w * 16;
        short* Kd = &SM[buf * 4096];
        short* Vd = &SM[8192 + buf * 4096];
        load_lds16(&kb[hb + (size_t)(k0 + rb + lr) * 64 + ck * 8],       &Kd[rb * 64]);
        load_lds16(&kb[hb + (size_t)(k0 + rb + 8 + lr) * 64 + ck * 8],   &Kd[(rb + 8) * 64]);
        load_lds16(&vt[hb + (size_t)(rb + lr) * 2048 + k0 + ck * 8],     &Vd[rb * 64]);
        load_lds16(&vt[hb + (size_t)(rb + 8 + lr) * 2048 + k0 + ck * 8], &Vd[(rb + 8) * 64]);
    };
    stageKV(0, 0);
    wait_vm0_barrier();

    float m_ = -1e30f, l_ = 0.f;
    f32x16 o0 = (f32x16)(0.f), o1 = (f32x16)(0.f);   // O^T d-blocks 0/1; col q = lane&31
    int cur = 0;

    for (int t = 0; t < 32; t++) {
        if (t + 1 < 32) stageKV(cur ^ 1, t + 1);
        const short* Kc = &SM[cur * 4096];
        const short* Vc = &SM[8192 + cur * 4096];

        // ---- QK^T: S^T[key][q]; key = (r&3)+8*(r>>2)+4*hi (+32 for s1) ----
        f32x16 s0 = (f32x16)(0.f), s1 = (f32x16)(0.f);
        {
            int r0 = l31, r1 = 32 + l31;
            int cshift = (l31 & 7);
#pragma unroll
            for (int ds = 0; ds < 4; ds++) {
                bf16x8 k0f = *(const bf16x8*)&Kc[r0 * 64 + ((2 * ds + hi) ^ cshift) * 8];
                bf16x8 k1f = *(const bf16x8*)&Kc[r1 * 64 + ((2 * ds + hi) ^ cshift) * 8];
                s0 = MFMA32(k0f, qf[ds], s0, 0, 0, 0);
                s1 = MFMA32(k1f, qf[ds], s1, 0, 0, 0);
            }
        }

        // ---- row max over own 32 values + partner exchange ----
        float q0m = fmaxf(fmaxf(s0[0], s0[1]),  fmaxf(s0[2], s0[3]));
        float q1m = fmaxf(fmaxf(s0[4], s0[5]),  fmaxf(s0[6], s0[7]));
        float q2m = fmaxf(fmaxf(s0[8], s0[9]),  fmaxf(s0[10], s0[11]));
        float q3m = fmaxf(fmaxf(s0[12], s0[13]), fmaxf(s0[14], s0[15]));
        float q4m = fmaxf(fmaxf(s1[0], s1[1]),  fmaxf(s1[2], s1[3]));
        float q5m = fmaxf(fmaxf(s1[4], s1[5]),  fmaxf(s1[6], s1[7]));
        float q6m = fmaxf(fmaxf(s1[8], s1[9]),  fmaxf(s1[10], s1[11]));
        float q7m = fmaxf(fmaxf(s1[12], s1[13]), fmaxf(s1[14], s1[15]));
        float om = fmaxf(fmaxf(fmaxf(q0m, q1m), fmaxf(q2m, q3m)),
                         fmaxf(fmaxf(q4m, q5m), fmaxf(q6m, q7m)));
        unsigned ua = __float_as_uint(om), ub = ua;
        permswap(ua, ub);
        float pm = fmaxf(__uint_as_float(ua), __uint_as_float(ub));

        if (!__all(pm - m_ <= 8.f)) {   // defer-max THR=8
            float mn = fmaxf(m_, pm);
            float al = exp2_fast(m_ - mn);
            l_ *= al;
            o0 *= al;
            o1 *= al;
            m_ = mn;
        }

        // ---- exp (exp2 domain; Q pre-scaled by 0.125*log2e) + own-half sum ----
        float rs = 0.f;
#pragma unroll
        for (int r = 0; r < 16; r++) { s0[r] = exp2_fast(s0[r] - m_); rs += s0[r]; }
#pragma unroll
        for (int r = 0; r < 16; r++) { s1[r] = exp2_fast(s1[r] - m_); rs += s1[r]; }
        l_ += rs;

        // ---- P fragments in-register (cvt_pk + permlane32_swap) ----
        bf16x8 pf[4];
#pragma unroll
        for (int ks = 0; ks < 2; ks++) {
            unsigned X0 = pack_bf2(s0[8 * ks + 0], s0[8 * ks + 1]);
            unsigned X1 = pack_bf2(s0[8 * ks + 2], s0[8 * ks + 3]);
            unsigned Y0 = pack_bf2(s0[8 * ks + 4], s0[8 * ks + 5]);
            unsigned Y1 = pack_bf2(s0[8 * ks + 6], s0[8 * ks + 7]);
            permswap(X0, Y0);
            permswap(X1, Y1);
            pf[ks] = mk_frag(X0, X1, Y0, Y1);
        }
#pragma unroll
        for (int ks = 0; ks < 2; ks++) {
            unsigned X0 = pack_bf2(s1[8 * ks + 0], s1[8 * ks + 1]);
            unsigned X1 = pack_bf2(s1[8 * ks + 2], s1[8 * ks + 3]);
            unsigned Y0 = pack_bf2(s1[8 * ks + 4], s1[8 * ks + 5]);
            unsigned Y1 = pack_bf2(s1[8 * ks + 6], s1[8 * ks + 7]);
            permswap(X0, Y0);
            permswap(X1, Y1);
            pf[2 + ks] = mk_frag(X0, X1, Y0, Y1);
        }

        // ---- PV: O^T[d][q] += V^T_frag @ P_frag ----
        {
            int r0 = l31, r1 = 32 + l31;
            int cs0 = r0 & 7, cs1 = r1 & 7;
#pragma unroll
            for (int kk = 0; kk < 4; kk++) {
                int kc = 2 * kk + hi;
                bf16x8 v0f = *(const bf16x8*)&Vc[r0 * 64 + (kc ^ cs0) * 8];
                bf16x8 v1f = *(const bf16x8*)&Vc[r1 * 64 + (kc ^ cs1) * 8];
                o0 = MFMA32(v0f, pf[kk], o0, 0, 0, 0);
                o1 = MFMA32(v1f, pf[kk], o1, 0, 0, 0);
            }
        }

        wait_vm0_barrier();
        cur ^= 1;
    }

    // ---- epilogue: partner-half l sum, normalize, store ----
    unsigned sa = __float_as_uint(l_), sb = sa;
    permswap(sa, sb);
    float inv = 1.f / (__uint_as_float(sa) + __uint_as_float(sb));
    int q = q0 + 32 * w + l31;
    size_t obase = ((size_t)b * 2048 + q) * 512 + h * 64;
#pragma unroll
    for (int rr = 0; rr < 4; rr++) {
        int d0 = 8 * rr + 4 * hi;    // d = (r&3) + 8*(r>>2) + 4*hi
        unsigned long long pv =
            (unsigned long long)pack_bf2(o0[4 * rr + 0] * inv, o0[4 * rr + 1] * inv)
          | ((unsigned long long)pack_bf2(o0[4 * rr + 2] * inv, o0[4 * rr + 3] * inv) << 32);
        *(unsigned long long*)&outb[obase + d0] = pv;
        unsigned long long pv2 =
            (unsigned long long)pack_bf2(o1[4 * rr + 0] * inv, o1[4 * rr + 1] * inv)
          | ((unsigned long long)pack_bf2(o1[4 * rr + 2] * inv, o1[4 * rr + 3] * inv) << 32);
        *(unsigned long long*)&outb[obase + 32 + d0] = pv2;
    }
}

extern "C" void kernel_launch(void* const* d_in, const int* in_sizes, int n_in,
                              void* d_out, int out_size, void* d_ws, size_t ws_size,
                              hipStream_t stream) {
    const float* x      = (const float*)d_in[0];
    const float* ln1_w  = (const float*)d_in[1];
    const float* ln1_b  = (const float*)d_in[2];
    const float* ln2_w  = (const float*)d_in[3];
    const float* ln2_b  = (const float*)d_in[4];
    const float* wq     = (const float*)d_in[5];
    const float* wk     = (const float*)d_in[6];
    const float* wv     = (const float*)d_in[7];
    const float* wo     = (const float*)d_in[8];
    const float* w_gate = (const float*)d_in[9];
    const float* w_up   = (const float*)d_in[10];
    const float* w_down = (const float*)d_in[11];
    float* out = (float*)d_out;

    const int M = 4 * 2048;
    char* ws = (char*)d_ws;
    const size_t MB = 1 << 20;
    short* h1b   = (short*)(ws);               // 8 MB
    short* qb    = (short*)(ws + 8 * MB);      // 8 MB (h2b reuse after attn)
    short* kb    = (short*)(ws + 16 * MB);     // 8 MB (qb + 4194304)
    short* vt    = (short*)(ws + 24 * MB);     // 8 MB (qb + 2*4194304), [b,h,d,l]
    short* aob   = (short*)(ws + 40 * MB);     // 8 MB
    short* u_b   = (short*)(ws + 48 * MB);     // 16 MB
    short* qkvT  = (short*)(ws + 80 * MB);     // 1.5 MB: wq|wk|wv rows
    short* woT   = (short*)(ws + 82 * MB);     // 0.5 MB
    short* wguT  = (short*)(ws + 83 * MB);     // 2 MB: gate|up rows
    short* wdT   = (short*)(ws + 85 * MB);     // 1 MB
    short* h2b   = qb;

    WT7 wt;
    wt.a[0] = {wq,     qkvT,               512,  512};
    wt.a[1] = {wk,     qkvT + 512 * 512,   512,  512};
    wt.a[2] = {wv,     qkvT + 1024 * 512,  512,  512};
    wt.a[3] = {wo,     woT,                512,  512};
    wt.a[4] = {w_gate, wguT,               512, 1024};
    wt.a[5] = {w_up,   wguT + 1024 * 512,  512, 1024};
    wt.a[6] = {w_down, wdT,               1024,  512};

    // fused: ln1 (blocks 0..2047) + all weight transposes (blocks 2048..4607)
    prep_kernel<<<4608, 256, 0, stream>>>(x, ln1_w, ln1_b, h1b, wt);
    // qkv: q,k packed; v direct-transposed (no transp_v kernel)
    gemm_mfma<2, 128, 128><<<dim3(12, 64), 256, 0, stream>>>(h1b, qkvT, nullptr, qb, M, 1536, 512);
    attn_mfma_kernel<<<dim3(16, 32), 256, 0, stream>>>(qb, kb, vt, aob);
    gemm_mfma<0, 128, 64><<<dim3(8, 64), 256, 0, stream>>>(aob, woT, x, out, M, 512, 512);
    ln_kernel_b<<<M / 4, 256, 0, stream>>>(out, ln2_w, ln2_b, h2b);
    ffn_gateup_kernel<<<dim3(16, 64), 256, 0, stream>>>(h2b, wguT, wguT + 1024 * 512, u_b, M, 1024, 512);
    gemm_mfma<0, 128, 64><<<dim3(8, 64), 256, 0, stream>>>(u_b, wdT, out, out, M, 512, 1024);
}

// Round 14
// 155.635 us; speedup vs baseline: 1.0339x; 1.0339x over previous
//
#include <hip/hip_runtime.h>
#include <hip/hip_bf16.h>
#include <math.h>

#define EPS 1e-5f

typedef __attribute__((ext_vector_type(8))) short bf16x8;
typedef __attribute__((ext_vector_type(4))) float f32x4;
typedef __attribute__((ext_vector_type(16))) float f32x16;

#define MFMA16 __builtin_amdgcn_mfma_f32_16x16x32_bf16
#define MFMA32 __builtin_amdgcn_mfma_f32_32x32x16_bf16

__device__ __forceinline__ short f2bf(float x) {
    union { float f; unsigned u; } un; un.f = x;
    unsigned r = un.u + 0x7FFF + ((un.u >> 16) & 1);  // RNE
    return (short)(r >> 16);
}
__device__ __forceinline__ float bf2f(short s) {
    union { unsigned u; float f; } un;
    un.u = ((unsigned)(unsigned short)s) << 16;
    return un.f;
}
__device__ __forceinline__ unsigned pack_bf2(float a, float b) {
    unsigned r;
    asm("v_cvt_pk_bf16_f32 %0, %1, %2" : "=v"(r) : "v"(a), "v"(b));
    return r;
}
__device__ __forceinline__ float exp2_fast(float x) {
    float r;
    asm("v_exp_f32 %0, %1" : "=v"(r) : "v"(x));
    return r;
}
// v_permlane32_swap_b32: a.hi-lanes <-> b.lo-lanes (both modified)
__device__ __forceinline__ void permswap(unsigned& a, unsigned& b) {
    asm volatile("v_permlane32_swap_b32 %0, %1" : "+v"(a), "+v"(b));
}
__device__ __forceinline__ bf16x8 mk_frag(unsigned a, unsigned b, unsigned c, unsigned d) {
    union { unsigned u[4]; bf16x8 v; } t;
    t.u[0] = a; t.u[1] = b; t.u[2] = c; t.u[3] = d;
    return t.v;
}
__device__ __forceinline__ void load_lds16(const short* g, short* l) {
    __builtin_amdgcn_global_load_lds(
        (const __attribute__((address_space(1))) unsigned int*)g,
        (__attribute__((address_space(3))) unsigned int*)l, 16, 0, 0);
}
__device__ __forceinline__ void wait_vm0_barrier() {
    asm volatile("s_waitcnt vmcnt(0)" ::: "memory");
    __builtin_amdgcn_s_barrier();
    __builtin_amdgcn_sched_barrier(0);
}

// ---------------- LayerNorm: fp32 -> bf16, one WAVE per row, 4 rows/block ----------------
__global__ __launch_bounds__(256) void ln_kernel_b(const float* __restrict__ in,
                                                   const float* __restrict__ w,
                                                   const float* __restrict__ bb,
                                                   short* __restrict__ out) {
    int wv = threadIdx.x >> 6, lane = threadIdx.x & 63;
    int row = blockIdx.x * 4 + wv;
    const float* x = in + (size_t)row * 512 + lane * 8;
    float4 v0 = *(const float4*)x;
    float4 v1 = *(const float4*)(x + 4);
    float s  = (v0.x + v0.y) + (v0.z + v0.w) + (v1.x + v1.y) + (v1.z + v1.w);
    float s2 = v0.x*v0.x + v0.y*v0.y + v0.z*v0.z + v0.w*v0.w
             + v1.x*v1.x + v1.y*v1.y + v1.z*v1.z + v1.w*v1.w;
#pragma unroll
    for (int off = 1; off < 64; off <<= 1) {
        s  += __shfl_xor(s, off);
        s2 += __shfl_xor(s2, off);
    }
    float mu = s * (1.f / 512.f);
    float rstd = rsqrtf(s2 * (1.f / 512.f) - mu * mu + EPS);
    const float4 wa = *(const float4*)&w[lane * 8];
    const float4 wb = *(const float4*)&w[lane * 8 + 4];
    const float4 ba = *(const float4*)&bb[lane * 8];
    const float4 bv = *(const float4*)&bb[lane * 8 + 4];
    uint4 o;
    o.x = pack_bf2((v0.x - mu) * rstd * wa.x + ba.x, (v0.y - mu) * rstd * wa.y + ba.y);
    o.y = pack_bf2((v0.z - mu) * rstd * wa.z + ba.z, (v0.w - mu) * rstd * wa.w + ba.w);
    o.z = pack_bf2((v1.x - mu) * rstd * wb.x + bv.x, (v1.y - mu) * rstd * wb.y + bv.y);
    o.w = pack_bf2((v1.z - mu) * rstd * wb.z + bv.z, (v1.w - mu) * rstd * wb.w + bv.w);
    *(uint4*)&out[(size_t)row * 512 + lane * 8] = o;
}

// ---------------- weight transpose+cast: w[K][N] fp32 -> bt[N][K] bf16 (7 at once) ----------------
struct WT { const float* w; short* t; int K; int N; };
struct WT7 { WT a[7]; };
__global__ __launch_bounds__(256) void transp_w_kernel(WT7 p) {
    WT e = p.a[blockIdx.z];
    int k0 = blockIdx.x * 32, n0 = blockIdx.y * 32;
    if (k0 >= e.K || n0 >= e.N) return;
    __shared__ short t[32][33];
    int tx = threadIdx.x & 31, ty = threadIdx.x >> 5;  // 32 x 8
#pragma unroll
    for (int pp = 0; pp < 4; pp++)
        t[pp * 8 + ty][tx] = f2bf(e.w[(size_t)(k0 + pp * 8 + ty) * e.N + n0 + tx]);
    __syncthreads();
#pragma unroll
    for (int pp = 0; pp < 4; pp++)
        e.t[(size_t)(n0 + pp * 8 + ty) * e.K + k0 + tx] = t[tx][pp * 8 + ty];
}

// ---------------- bf16 MFMA GEMM: C[M,N] = A[M,K] @ Bt[N,K]^T ----------------
// 128xBN tile, BK=64, 4 waves 2x2, double-buffered LDS, 2-phase pipeline
// (stage(t+1) -> compute(t) -> vmcnt(0)+barrier), XCD swizzle.
// EPI: 0 = fp32 C = res + acc (row-major)
//      2 = bf16 qkv packed [b,h,l,d]; q (n<512) pre-scaled by 0.125*log2e
template <int EPI, int BM, int BN>
__global__ __launch_bounds__(256) void gemm_mfma(const short* __restrict__ A,
                                                 const short* __restrict__ Bt,
                                                 const float* __restrict__ res,
                                                 void* __restrict__ Cv,
                                                 int M, int N, int K) {
    constexpr int MI = BM >> 5;
    constexpr int NJ = BN >> 5;
    __shared__ short As[2][BM * 64];
    __shared__ short Bs[2][BN * 64];
    const int tid = threadIdx.x;
    const int lane = tid & 63, w = tid >> 6;
    const int g = lane >> 4, r16 = lane & 15;
    const int wr = w >> 1, wc = w & 1;

    // XCD-aware bijective swizzle (grid size divisible by 8)
    const int nb = gridDim.x * gridDim.y;
    const int fid = blockIdx.y * gridDim.x + blockIdx.x;
    const int nid = (fid & 7) * (nb >> 3) + (fid >> 3);
    const int m0 = (nid / gridDim.x) * BM, n0 = (nid % gridDim.x) * BN;

    const int lr = lane >> 3;        // row within 8-row group
    const int ck = (lane & 7) ^ lr;  // inverse-swizzled source chunk

    auto stage = [&](int buf, int k0) {
#pragma unroll
        for (int p = 0; p < BM / 32; p++) {
            int rb = w * (BM / 4) + p * 8;
            load_lds16(&A[(size_t)(m0 + rb + lr) * K + k0 + ck * 8], &As[buf][rb * 64]);
        }
#pragma unroll
        for (int p = 0; p < BN / 32; p++) {
            int rb = w * (BN / 4) + p * 8;
            load_lds16(&Bt[(size_t)(n0 + rb + lr) * K + k0 + ck * 8], &Bs[buf][rb * 64]);
        }
    };

    f32x4 acc[MI][NJ] = {};
    stage(0, 0);
    wait_vm0_barrier();

    const int nt = K >> 6;
    int cur = 0;
    for (int t = 0; t < nt; t++) {
        if (t + 1 < nt) stage(cur ^ 1, (t + 1) << 6);
#pragma unroll
        for (int ks = 0; ks < 2; ks++) {
            bf16x8 av[MI], bv[NJ];
#pragma unroll
            for (int i = 0; i < MI; i++) {
                int row = wr * (BM >> 1) + i * 16 + r16;
                av[i] = *(const bf16x8*)&As[cur][row * 64 + ((ks * 4 + g) ^ (row & 7)) * 8];
            }
#pragma unroll
            for (int j = 0; j < NJ; j++) {
                int row = wc * (BN >> 1) + j * 16 + r16;
                bv[j] = *(const bf16x8*)&Bs[cur][row * 64 + ((ks * 4 + g) ^ (row & 7)) * 8];
            }
#pragma unroll
            for (int i = 0; i < MI; i++)
#pragma unroll
                for (int j = 0; j < NJ; j++)
                    acc[i][j] = MFMA16(av[i], bv[j], acc[i][j], 0, 0, 0);
        }
        wait_vm0_barrier();
        cur ^= 1;
    }

#pragma unroll
    for (int i = 0; i < MI; i++)
#pragma unroll
        for (int j = 0; j < NJ; j++)
#pragma unroll
            for (int jr = 0; jr < 4; jr++) {
                int m = m0 + wr * (BM >> 1) + i * 16 + 4 * g + jr;
                int n = n0 + wc * (BN >> 1) + j * 16 + r16;
                float v = acc[i][j][jr];
                if (EPI == 0) {
                    size_t idx = (size_t)m * N + n;
                    ((float*)Cv)[idx] = res[idx] + v;
                } else {
                    if (n < 512) v *= 0.18033688011112042f;  // 0.125 * log2(e)
                    ((short*)Cv)[(size_t)(n >> 9) * 4194304 +
                                 (((size_t)(m >> 11) * 8 + ((n >> 6) & 7)) * 2048 + (m & 2047)) * 64 + (n & 63)] = f2bf(v);
                }
            }
}

// ---------------- fused FFN gate+up GEMM + silu: u = silu(A@Wg^T) * (A@Wu^T) ----------------
// 128x64 tile, BK=64, both B-panels staged, two accumulator sets; silu on fp32 gate.
__global__ __launch_bounds__(256) void ffn_gateup_kernel(const short* __restrict__ A,
                                                         const short* __restrict__ Bg,
                                                         const short* __restrict__ Bu,
                                                         short* __restrict__ U,
                                                         int M, int N, int K) {
    constexpr int MI = 4, NJ = 2;  // BM=128, BN=64
    __shared__ short As[2][128 * 64];
    __shared__ short Bgs[2][64 * 64];
    __shared__ short Bus[2][64 * 64];
    const int tid = threadIdx.x;
    const int lane = tid & 63, w = tid >> 6;
    const int g = lane >> 4, r16 = lane & 15;
    const int wr = w >> 1, wc = w & 1;

    const int nb = gridDim.x * gridDim.y;
    const int fid = blockIdx.y * gridDim.x + blockIdx.x;
    const int nid = (fid & 7) * (nb >> 3) + (fid >> 3);
    const int m0 = (nid / gridDim.x) * 128, n0 = (nid % gridDim.x) * 64;

    const int lr = lane >> 3;
    const int ck = (lane & 7) ^ lr;

    auto stage = [&](int buf, int k0) {
#pragma unroll
        for (int p = 0; p < 4; p++) {
            int rb = w * 32 + p * 8;
            load_lds16(&A[(size_t)(m0 + rb + lr) * K + k0 + ck * 8], &As[buf][rb * 64]);
        }
#pragma unroll
        for (int p = 0; p < 2; p++) {
            int rb = w * 16 + p * 8;
            load_lds16(&Bg[(size_t)(n0 + rb + lr) * K + k0 + ck * 8], &Bgs[buf][rb * 64]);
            load_lds16(&Bu[(size_t)(n0 + rb + lr) * K + k0 + ck * 8], &Bus[buf][rb * 64]);
        }
    };

    f32x4 accg[MI][NJ] = {};
    f32x4 accu[MI][NJ] = {};
    stage(0, 0);
    wait_vm0_barrier();

    const int nt = K >> 6;
    int cur = 0;
    for (int t = 0; t < nt; t++) {
        if (t + 1 < nt) stage(cur ^ 1, (t + 1) << 6);
#pragma unroll
        for (int ks = 0; ks < 2; ks++) {
            bf16x8 av[MI], bgv[NJ], buv[NJ];
#pragma unroll
            for (int i = 0; i < MI; i++) {
                int row = wr * 64 + i * 16 + r16;
                av[i] = *(const bf16x8*)&As[cur][row * 64 + ((ks * 4 + g) ^ (row & 7)) * 8];
            }
#pragma unroll
            for (int j = 0; j < NJ; j++) {
                int row = wc * 32 + j * 16 + r16;
                int off = row * 64 + ((ks * 4 + g) ^ (row & 7)) * 8;
                bgv[j] = *(const bf16x8*)&Bgs[cur][off];
                buv[j] = *(const bf16x8*)&Bus[cur][off];
            }
#pragma unroll
            for (int i = 0; i < MI; i++)
#pragma unroll
                for (int j = 0; j < NJ; j++) {
                    accg[i][j] = MFMA16(av[i], bgv[j], accg[i][j], 0, 0, 0);
                    accu[i][j] = MFMA16(av[i], buv[j], accu[i][j], 0, 0, 0);
                }
        }
        wait_vm0_barrier();
        cur ^= 1;
    }

#pragma unroll
    for (int i = 0; i < MI; i++)
#pragma unroll
        for (int j = 0; j < NJ; j++)
#pragma unroll
            for (int jr = 0; jr < 4; jr++) {
                int m = m0 + wr * 64 + i * 16 + 4 * g + jr;
                int n = n0 + wc * 32 + j * 16 + r16;
                float gt = accg[i][j][jr];
                float y = gt / (1.f + __expf(-gt)) * accu[i][j][jr];
                U[(size_t)m * N + n] = f2bf(y);
            }
}

// ---------------- bf16 transpose V: [b,h,l,d] -> [b,h,d,l] ----------------
__global__ __launch_bounds__(256) void transp_v_kernel(const short* __restrict__ vb,
                                                       short* __restrict__ vt) {
    __shared__ short tile[64][65];
    int l0 = blockIdx.x * 64;
    int bh = blockIdx.y;
    const size_t base = (size_t)bh * 2048 * 64;
    int tid = threadIdx.x;
#pragma unroll
    for (int p = 0; p < 4; p++) {
        int r = p * 16 + (tid >> 4);
        int c4 = (tid & 15) * 4;
        *(short4*)&tile[r][c4] = *(const short4*)&vb[base + (size_t)(l0 + r) * 64 + c4];
    }
    __syncthreads();
#pragma unroll
    for (int p = 0; p < 4; p++) {
        int d = p * 16 + (tid >> 4);
        int c4 = (tid & 15) * 4;
        short4 o;
        o.x = tile[c4 + 0][d]; o.y = tile[c4 + 1][d];
        o.z = tile[c4 + 2][d]; o.w = tile[c4 + 3][d];
        *(short4*)&vt[base + (size_t)d * 2048 + l0 + c4] = o;
    }
}

// ---------------- MFMA flash attention: 32x32 swapped-QK, in-register softmax ----------------
// grid 512 (XCD-swizzled, bh-major), 4 waves, 32 q-rows/wave (Q-tile 128), KVBLK 64.
// Sequential over full L (numerics-proven, absmax 0.109). S^T = mfma32(K, Q): lane
// owns q = lane&31. P in-register via cvt_pk + permlane32_swap; O^T = mfma32(V^T, P).
__global__ __launch_bounds__(256) void attn_mfma_kernel(const short* __restrict__ qb,
                                                        const short* __restrict__ kb,
                                                        const short* __restrict__ vt,
                                                        short* __restrict__ outb) {
    __shared__ short SM[16384];  // [0,8K)=K dbuf, [8K,16K)=V dbuf (Q staged here first)

    const int fid = blockIdx.y * gridDim.x + blockIdx.x;   // grid (16, 32)
    const int nid = (fid & 7) * 64 + (fid >> 3);           // bh-major within XCD
    const int bh = nid >> 4, qt = nid & 15;
    const int b = bh >> 3, h = bh & 7;
    const int q0 = qt * 128;
    const size_t hb = (size_t)bh * (2048 * 64);

    const int tid = threadIdx.x;
    const int lane = tid & 63, w = tid >> 6;
    const int hi = lane >> 5;
    const int l31 = lane & 31;
    const int lr = lane >> 3, ck = (lane & 7) ^ lr;

    // ---- stage Q (wave w -> rows 32w..32w+31) into V-buffer area, then to regs ----
#pragma unroll
    for (int p = 0; p < 4; p++)
        load_lds16(&qb[hb + (size_t)(q0 + 32 * w + 8 * p + lr) * 64 + ck * 8],
                   &SM[8192 + (32 * w + 8 * p) * 64]);
    wait_vm0_barrier();
    bf16x8 qf[4];
    {
        int row = 32 * w + l31;
#pragma unroll
        for (int ds = 0; ds < 4; ds++)
            qf[ds] = *(const bf16x8*)&SM[8192 + row * 64 + ((2 * ds + hi) ^ (row & 7)) * 8];
    }
    asm volatile("s_waitcnt lgkmcnt(0)" ::: "memory");
    __builtin_amdgcn_s_barrier();
    __builtin_amdgcn_sched_barrier(0);

    auto stageKV = [&](int buf, int kt) {
        int k0 = kt * 64;
        int rb = w * 16;
        short* Kd = &SM[buf * 4096];
        short* Vd = &SM[8192 + buf * 4096];
        load_lds16(&kb[hb + (size_t)(k0 + rb + lr) * 64 + ck * 8],       &Kd[rb * 64]);
        load_lds16(&kb[hb + (size_t)(k0 + rb + 8 + lr) * 64 + ck * 8],   &Kd[(rb + 8) * 64]);
        load_lds16(&vt[hb + (size_t)(rb + lr) * 2048 + k0 + ck * 8],     &Vd[rb * 64]);
        load_lds16(&vt[hb + (size_t)(rb + 8 + lr) * 2048 + k0 + ck * 8], &Vd[(rb + 8) * 64]);
    };
    stageKV(0, 0);
    wait_vm0_barrier();

    float m_ = -1e30f, l_ = 0.f;
    f32x16 o0 = (f32x16)(0.f), o1 = (f32x16)(0.f);   // O^T d-blocks 0/1; col q = lane&31
    int cur = 0;

    for (int t = 0; t < 32; t++) {
        if (t + 1 < 32) stageKV(cur ^ 1, t + 1);
        const short* Kc = &SM[cur * 4096];
        const short* Vc = &SM[8192 + cur * 4096];

        // ---- QK^T: S^T[key][q]; key = (r&3)+8*(r>>2)+4*hi (+32 for s1) ----
        f32x16 s0 = (f32x16)(0.f), s1 = (f32x16)(0.f);
        {
            int r0 = l31, r1 = 32 + l31;
            int cshift = (l31 & 7);
#pragma unroll
            for (int ds = 0; ds < 4; ds++) {
                bf16x8 k0f = *(const bf16x8*)&Kc[r0 * 64 + ((2 * ds + hi) ^ cshift) * 8];
                bf16x8 k1f = *(const bf16x8*)&Kc[r1 * 64 + ((2 * ds + hi) ^ cshift) * 8];
                s0 = MFMA32(k0f, qf[ds], s0, 0, 0, 0);
                s1 = MFMA32(k1f, qf[ds], s1, 0, 0, 0);
            }
        }

        // ---- row max over own 32 values + partner exchange ----
        float q0m = fmaxf(fmaxf(s0[0], s0[1]),  fmaxf(s0[2], s0[3]));
        float q1m = fmaxf(fmaxf(s0[4], s0[5]),  fmaxf(s0[6], s0[7]));
        float q2m = fmaxf(fmaxf(s0[8], s0[9]),  fmaxf(s0[10], s0[11]));
        float q3m = fmaxf(fmaxf(s0[12], s0[13]), fmaxf(s0[14], s0[15]));
        float q4m = fmaxf(fmaxf(s1[0], s1[1]),  fmaxf(s1[2], s1[3]));
        float q5m = fmaxf(fmaxf(s1[4], s1[5]),  fmaxf(s1[6], s1[7]));
        float q6m = fmaxf(fmaxf(s1[8], s1[9]),  fmaxf(s1[10], s1[11]));
        float q7m = fmaxf(fmaxf(s1[12], s1[13]), fmaxf(s1[14], s1[15]));
        float om = fmaxf(fmaxf(fmaxf(q0m, q1m), fmaxf(q2m, q3m)),
                         fmaxf(fmaxf(q4m, q5m), fmaxf(q6m, q7m)));
        unsigned ua = __float_as_uint(om), ub = ua;
        permswap(ua, ub);
        float pm = fmaxf(__uint_as_float(ua), __uint_as_float(ub));

        if (!__all(pm - m_ <= 8.f)) {   // defer-max THR=8
            float mn = fmaxf(m_, pm);
            float al = exp2_fast(m_ - mn);
            l_ *= al;
            o0 *= al;
            o1 *= al;
            m_ = mn;
        }

        // ---- exp (exp2 domain; Q pre-scaled by 0.125*log2e) + own-half sum ----
        float rs = 0.f;
#pragma unroll
        for (int r = 0; r < 16; r++) { s0[r] = exp2_fast(s0[r] - m_); rs += s0[r]; }
#pragma unroll
        for (int r = 0; r < 16; r++) { s1[r] = exp2_fast(s1[r] - m_); rs += s1[r]; }
        l_ += rs;

        // ---- P fragments in-register (cvt_pk + permlane32_swap) ----
        bf16x8 pf[4];
#pragma unroll
        for (int ks = 0; ks < 2; ks++) {
            unsigned X0 = pack_bf2(s0[8 * ks + 0], s0[8 * ks + 1]);
            unsigned X1 = pack_bf2(s0[8 * ks + 2], s0[8 * ks + 3]);
            unsigned Y0 = pack_bf2(s0[8 * ks + 4], s0[8 * ks + 5]);
            unsigned Y1 = pack_bf2(s0[8 * ks + 6], s0[8 * ks + 7]);
            permswap(X0, Y0);
            permswap(X1, Y1);
            pf[ks] = mk_frag(X0, X1, Y0, Y1);
        }
#pragma unroll
        for (int ks = 0; ks < 2; ks++) {
            unsigned X0 = pack_bf2(s1[8 * ks + 0], s1[8 * ks + 1]);
            unsigned X1 = pack_bf2(s1[8 * ks + 2], s1[8 * ks + 3]);
            unsigned Y0 = pack_bf2(s1[8 * ks + 4], s1[8 * ks + 5]);
            unsigned Y1 = pack_bf2(s1[8 * ks + 6], s1[8 * ks + 7]);
            permswap(X0, Y0);
            permswap(X1, Y1);
            pf[2 + ks] = mk_frag(X0, X1, Y0, Y1);
        }

        // ---- PV: O^T[d][q] += V^T_frag @ P_frag ----
        {
            int r0 = l31, r1 = 32 + l31;
            int cs0 = r0 & 7, cs1 = r1 & 7;
#pragma unroll
            for (int kk = 0; kk < 4; kk++) {
                int kc = 2 * kk + hi;
                bf16x8 v0f = *(const bf16x8*)&Vc[r0 * 64 + (kc ^ cs0) * 8];
                bf16x8 v1f = *(const bf16x8*)&Vc[r1 * 64 + (kc ^ cs1) * 8];
                o0 = MFMA32(v0f, pf[kk], o0, 0, 0, 0);
                o1 = MFMA32(v1f, pf[kk], o1, 0, 0, 0);
            }
        }

        wait_vm0_barrier();
        cur ^= 1;
    }

    // ---- epilogue: partner-half l sum, normalize, store ----
    unsigned sa = __float_as_uint(l_), sb = sa;
    permswap(sa, sb);
    float inv = 1.f / (__uint_as_float(sa) + __uint_as_float(sb));
    int q = q0 + 32 * w + l31;
    size_t obase = ((size_t)b * 2048 + q) * 512 + h * 64;
#pragma unroll
    for (int rr = 0; rr < 4; rr++) {
        int d0 = 8 * rr + 4 * hi;    // d = (r&3) + 8*(r>>2) + 4*hi
        unsigned long long pv =
            (unsigned long long)pack_bf2(o0[4 * rr + 0] * inv, o0[4 * rr + 1] * inv)
          | ((unsigned long long)pack_bf2(o0[4 * rr + 2] * inv, o0[4 * rr + 3] * inv) << 32);
        *(unsigned long long*)&outb[obase + d0] = pv;
        unsigned long long pv2 =
            (unsigned long long)pack_bf2(o1[4 * rr + 0] * inv, o1[4 * rr + 1] * inv)
          | ((unsigned long long)pack_bf2(o1[4 * rr + 2] * inv, o1[4 * rr + 3] * inv) << 32);
        *(unsigned long long*)&outb[obase + 32 + d0] = pv2;
    }
}

extern "C" void kernel_launch(void* const* d_in, const int* in_sizes, int n_in,
                              void* d_out, int out_size, void* d_ws, size_t ws_size,
                              hipStream_t stream) {
    const float* x      = (const float*)d_in[0];
    const float* ln1_w  = (const float*)d_in[1];
    const float* ln1_b  = (const float*)d_in[2];
    const float* ln2_w  = (const float*)d_in[3];
    const float* ln2_b  = (const float*)d_in[4];
    const float* wq     = (const float*)d_in[5];
    const float* wk     = (const float*)d_in[6];
    const float* wv     = (const float*)d_in[7];
    const float* wo     = (const float*)d_in[8];
    const float* w_gate = (const float*)d_in[9];
    const float* w_up   = (const float*)d_in[10];
    const float* w_down = (const float*)d_in[11];
    float* out = (float*)d_out;

    const int M = 4 * 2048;
    char* ws = (char*)d_ws;
    const size_t MB = 1 << 20;
    short* h1b   = (short*)(ws);               // 8 MB
    short* qb    = (short*)(ws + 8 * MB);      // 8 MB (h2b reuse after attn)
    short* kb    = (short*)(ws + 16 * MB);     // 8 MB (qb + 4194304)
    short* vb    = (short*)(ws + 24 * MB);     // 8 MB (qb + 2*4194304)
    short* vt    = (short*)(ws + 32 * MB);     // 8 MB
    short* aob   = (short*)(ws + 40 * MB);     // 8 MB
    short* u_b   = (short*)(ws + 48 * MB);     // 16 MB
    short* qkvT  = (short*)(ws + 80 * MB);     // 1.5 MB: wq|wk|wv rows
    short* woT   = (short*)(ws + 82 * MB);     // 0.5 MB
    short* wguT  = (short*)(ws + 83 * MB);     // 2 MB: gate|up rows
    short* wdT   = (short*)(ws + 85 * MB);     // 1 MB
    short* h2b   = qb;

    WT7 wt;
    wt.a[0] = {wq,     qkvT,               512,  512};
    wt.a[1] = {wk,     qkvT + 512 * 512,   512,  512};
    wt.a[2] = {wv,     qkvT + 1024 * 512,  512,  512};
    wt.a[3] = {wo,     woT,                512,  512};
    wt.a[4] = {w_gate, wguT,               512, 1024};
    wt.a[5] = {w_up,   wguT + 1024 * 512,  512, 1024};
    wt.a[6] = {w_down, wdT,               1024,  512};

    transp_w_kernel<<<dim3(32, 32, 7), 256, 0, stream>>>(wt);
    ln_kernel_b<<<M / 4, 256, 0, stream>>>(x, ln1_w, ln1_b, h1b);
    gemm_mfma<2, 128, 128><<<dim3(12, 64), 256, 0, stream>>>(h1b, qkvT, nullptr, qb, M, 1536, 512);
    transp_v_kernel<<<dim3(32, 32), 256, 0, stream>>>(vb, vt);
    attn_mfma_kernel<<<dim3(16, 32), 256, 0, stream>>>(qb, kb, vt, aob);
    gemm_mfma<0, 128, 64><<<dim3(8, 64), 256, 0, stream>>>(aob, woT, x, out, M, 512, 512);
    ln_kernel_b<<<M / 4, 256, 0, stream>>>(out, ln2_w, ln2_b, h2b);
    ffn_gateup_kernel<<<dim3(16, 64), 256, 0, stream>>>(h2b, wguT, wguT + 1024 * 512, u_b, M, 1024, 512);
    gemm_mfma<0, 128, 64><<<dim3(8, 64), 256, 0, stream>>>(u_b, wdT, out, out, M, 512, 1024);
}